// Round 2
// baseline (60701.038 us; speedup 1.0000x reference)
//
#include <hip/hip_runtime.h>
#include <hip/hip_bf16.h>

// Problem: BATCH=128, SEQ=1024, DIN=512, HID=512 (all fp32)
// out = final hidden state (128, 512) of h_t = tanh(x_t@Wx + h_{t-1}@Wh + b)

#define BATCH 128
#define SEQ   1024
#define DIN   512
#define HID   512

typedef float v2f __attribute__((ext_vector_type(2)));

// ---------------------------------------------------------------------------
// Kernel 1: xp[s][b][j] = sum_d x[b][s][d] * Wx[d][j] + bias[j]
// Tiled fp32 GEMM, 64x64 tile, 256 threads, 4x4 microtile (packed-fp32 accs).
// ---------------------------------------------------------------------------
__global__ __launch_bounds__(256) void xp_gemm(
    const float* __restrict__ x, const float* __restrict__ Wx,
    const float* __restrict__ bias, float* __restrict__ xp,
    int s0)
{
    __shared__ __align__(16) float As[16][64 + 4];
    __shared__ __align__(16) float Bs[16][64];

    const int tid = threadIdx.x;
    const int tx = tid & 15;
    const int ty = tid >> 4;
    const int rowBase = blockIdx.x * 64;
    const int colBase = blockIdx.y * 64;

    const int a_r  = tid >> 2;
    const int a_k4 = (tid & 3) * 4;
    const int rr   = rowBase + a_r;
    const int s    = s0 + (rr >> 7);
    const int bb   = rr & 127;
    const float* a_row = x + ((size_t)bb * SEQ + s) * DIN;

    const int b_kk = tid >> 4;
    const int b_j4 = (tid & 15) * 4;

    v2f C[4][2] = {};

    for (int k0 = 0; k0 < DIN; k0 += 16) {
        float4 av = *reinterpret_cast<const float4*>(a_row + k0 + a_k4);
        As[a_k4 + 0][a_r] = av.x;
        As[a_k4 + 1][a_r] = av.y;
        As[a_k4 + 2][a_r] = av.z;
        As[a_k4 + 3][a_r] = av.w;
        float4 bv = *reinterpret_cast<const float4*>(Wx + (size_t)(k0 + b_kk) * HID + colBase + b_j4);
        *reinterpret_cast<float4*>(&Bs[b_kk][b_j4]) = bv;
        __syncthreads();

        #pragma unroll
        for (int kk = 0; kk < 16; ++kk) {
            float4 a4 = *reinterpret_cast<const float4*>(&As[kk][ty * 4]);
            float4 b4 = *reinterpret_cast<const float4*>(&Bs[kk][tx * 4]);
            v2f b01 = {b4.x, b4.y};
            v2f b23 = {b4.z, b4.w};
            float a[4] = {a4.x, a4.y, a4.z, a4.w};
            #pragma unroll
            for (int i = 0; i < 4; ++i) {
                C[i][0] += b01 * a[i];
                C[i][1] += b23 * a[i];
            }
        }
        __syncthreads();
    }

    float4 bias4 = *reinterpret_cast<const float4*>(bias + colBase + tx * 4);
    #pragma unroll
    for (int i = 0; i < 4; ++i) {
        int orow = rowBase + ty * 4 + i;
        float4 o;
        o.x = C[i][0].x + bias4.x;
        o.y = C[i][0].y + bias4.y;
        o.z = C[i][1].x + bias4.z;
        o.w = C[i][1].y + bias4.w;
        *reinterpret_cast<float4*>(xp + (size_t)orow * HID + colBase + tx * 4) = o;
    }
}

// ---------------------------------------------------------------------------
// Kernel 2: recurrence. 64 blocks x 512 threads, 2 batch rows/block.
//   thread = (k-group g = tid>>7, col-group c = tid&127) -> cols 4c..4c+3,
//   k-range [128g, 128g+128). RES k-rows held resident in VGPRs; the rest
//   streamed from L2 as float4 (fully unrolled -> deep load pipelining).
//   Packed v2f accumulators -> v_pk_fma_f32. LDS reduce across 4 k-groups.
// ---------------------------------------------------------------------------
#define RES  24          // register-resident k-rows per thread (96 VGPRs)
#define NSTR (128 - RES) // 104 streamed k-rows

__global__ __launch_bounds__(512, 2) void recur_kernel(
    const float* __restrict__ xp, const float* __restrict__ Wh,
    float* __restrict__ h_state, float* __restrict__ out,
    int steps, int init_h, int write_out)
{
    __shared__ __align__(16) float h0[HID];
    __shared__ __align__(16) float h1[HID];
    __shared__ float4 part[3][2][128];   // [g-1][row][c]

    const int tid = threadIdx.x;         // 0..511
    const int g = tid >> 7;              // k-group 0..3
    const int c = tid & 127;             // col group: cols 4c..4c+3
    const int b0 = blockIdx.x * 2;
    const int b1 = b0 + 1;

    if (init_h) {
        h0[tid] = 0.0f;
        h1[tid] = 0.0f;
    } else {
        h0[tid] = h_state[(size_t)b0 * HID + tid];
        h1[tid] = h_state[(size_t)b1 * HID + tid];
    }
    __syncthreads();

    const int kres = g * 128;
    const int kstr = g * 128 + RES;

    // Preload resident Wh rows into registers (loaded once, reused 1024x)
    const float* wres = Wh + (size_t)kres * HID + 4 * c;
    v2f wrA[RES], wrB[RES];
    #pragma unroll
    for (int r = 0; r < RES; ++r) {
        float4 w = *reinterpret_cast<const float4*>(wres + (size_t)r * HID);
        wrA[r] = (v2f){w.x, w.y};
        wrB[r] = (v2f){w.z, w.w};
    }
    const float* wstr = Wh + (size_t)kstr * HID + 4 * c;

    for (int s = 0; s < steps; ++s) {
        v2f a0A = {0.f, 0.f}, a0B = {0.f, 0.f};
        v2f a1A = {0.f, 0.f}, a1B = {0.f, 0.f};

        // --- resident k-rows ---
        #pragma unroll
        for (int r = 0; r < RES; r += 4) {
            float4 hv0 = *reinterpret_cast<const float4*>(&h0[kres + r]);
            float4 hv1 = *reinterpret_cast<const float4*>(&h1[kres + r]);
            a0A += wrA[r+0] * hv0.x;  a0B += wrB[r+0] * hv0.x;
            a1A += wrA[r+0] * hv1.x;  a1B += wrB[r+0] * hv1.x;
            a0A += wrA[r+1] * hv0.y;  a0B += wrB[r+1] * hv0.y;
            a1A += wrA[r+1] * hv1.y;  a1B += wrB[r+1] * hv1.y;
            a0A += wrA[r+2] * hv0.z;  a0B += wrB[r+2] * hv0.z;
            a1A += wrA[r+2] * hv1.z;  a1B += wrB[r+2] * hv1.z;
            a0A += wrA[r+3] * hv0.w;  a0B += wrB[r+3] * hv0.w;
            a1A += wrA[r+3] * hv1.w;  a1B += wrB[r+3] * hv1.w;
        }

        // --- streamed k-rows (fully unrolled: independent loads pipeline) ---
        #pragma unroll
        for (int i = 0; i < NSTR; i += 4) {
            float4 hv0 = *reinterpret_cast<const float4*>(&h0[kstr + i]);
            float4 hv1 = *reinterpret_cast<const float4*>(&h1[kstr + i]);
            float4 w0 = *reinterpret_cast<const float4*>(wstr + (size_t)(i+0) * HID);
            float4 w1 = *reinterpret_cast<const float4*>(wstr + (size_t)(i+1) * HID);
            float4 w2 = *reinterpret_cast<const float4*>(wstr + (size_t)(i+2) * HID);
            float4 w3 = *reinterpret_cast<const float4*>(wstr + (size_t)(i+3) * HID);
            v2f w0A = {w0.x, w0.y}, w0B = {w0.z, w0.w};
            v2f w1A = {w1.x, w1.y}, w1B = {w1.z, w1.w};
            v2f w2A = {w2.x, w2.y}, w2B = {w2.z, w2.w};
            v2f w3A = {w3.x, w3.y}, w3B = {w3.z, w3.w};
            a0A += w0A * hv0.x;  a0B += w0B * hv0.x;
            a1A += w0A * hv1.x;  a1B += w0B * hv1.x;
            a0A += w1A * hv0.y;  a0B += w1B * hv0.y;
            a1A += w1A * hv1.y;  a1B += w1B * hv1.y;
            a0A += w2A * hv0.z;  a0B += w2B * hv0.z;
            a1A += w2A * hv1.z;  a1B += w2B * hv1.z;
            a0A += w3A * hv0.w;  a0B += w3B * hv0.w;
            a1A += w3A * hv1.w;  a1B += w3B * hv1.w;
        }

        // --- reduce across k-groups via LDS ---
        if (g > 0) {
            part[g-1][0][c] = make_float4(a0A.x, a0A.y, a0B.x, a0B.y);
            part[g-1][1][c] = make_float4(a1A.x, a1A.y, a1B.x, a1B.y);
        }
        __syncthreads();
        if (g == 0) {
            #pragma unroll
            for (int gg = 0; gg < 3; ++gg) {
                float4 p0 = part[gg][0][c];
                float4 p1 = part[gg][1][c];
                a0A.x += p0.x; a0A.y += p0.y; a0B.x += p0.z; a0B.y += p0.w;
                a1A.x += p1.x; a1A.y += p1.y; a1B.x += p1.z; a1B.y += p1.w;
            }
            const float* xprow = xp + (size_t)s * (BATCH * HID);
            float4 x0 = *reinterpret_cast<const float4*>(xprow + (size_t)b0 * HID + 4 * c);
            float4 x1 = *reinterpret_cast<const float4*>(xprow + (size_t)b1 * HID + 4 * c);
            float4 n0, n1;
            n0.x = tanhf(a0A.x + x0.x);
            n0.y = tanhf(a0A.y + x0.y);
            n0.z = tanhf(a0B.x + x0.z);
            n0.w = tanhf(a0B.y + x0.w);
            n1.x = tanhf(a1A.x + x1.x);
            n1.y = tanhf(a1A.y + x1.y);
            n1.z = tanhf(a1B.x + x1.z);
            n1.w = tanhf(a1B.y + x1.w);
            *reinterpret_cast<float4*>(&h0[4 * c]) = n0;
            *reinterpret_cast<float4*>(&h1[4 * c]) = n1;
        }
        __syncthreads();
    }

    if (g == 0) {
        float4 f0 = *reinterpret_cast<const float4*>(&h0[4 * c]);
        float4 f1 = *reinterpret_cast<const float4*>(&h1[4 * c]);
        *reinterpret_cast<float4*>(h_state + (size_t)b0 * HID + 4 * c) = f0;
        *reinterpret_cast<float4*>(h_state + (size_t)b1 * HID + 4 * c) = f1;
        if (write_out) {
            *reinterpret_cast<float4*>(out + (size_t)b0 * HID + 4 * c) = f0;
            *reinterpret_cast<float4*>(out + (size_t)b1 * HID + 4 * c) = f1;
        }
    }
}

// ---------------------------------------------------------------------------
// Fallback (ws too small): fully fused, zero workspace. Unchanged from R1.
// ---------------------------------------------------------------------------
__global__ __launch_bounds__(512) void fused_kernel(
    const float* __restrict__ x, const float* __restrict__ Wx,
    const float* __restrict__ Wh, const float* __restrict__ bias,
    float* __restrict__ out)
{
    __shared__ __align__(16) float h0[HID];
    __shared__ __align__(16) float h1[HID];
    __shared__ __align__(16) float x0[DIN];
    __shared__ __align__(16) float x1[DIN];

    const int j = threadIdx.x;
    const int b0 = blockIdx.x * 2;
    const int b1 = b0 + 1;

    h0[j] = 0.0f;
    h1[j] = 0.0f;
    __syncthreads();

    const float4* h04 = reinterpret_cast<const float4*>(h0);
    const float4* h14 = reinterpret_cast<const float4*>(h1);
    const float4* x04 = reinterpret_cast<const float4*>(x0);
    const float4* x14 = reinterpret_cast<const float4*>(x1);

    for (int s = 0; s < SEQ; ++s) {
        x0[j] = x[((size_t)b0 * SEQ + s) * DIN + j];
        x1[j] = x[((size_t)b1 * SEQ + s) * DIN + j];
        __syncthreads();

        float acc0 = bias[j];
        float acc1 = bias[j];
        const float* wx = Wx + j;
        const float* wh = Wh + j;
        #pragma unroll 2
        for (int k4 = 0; k4 < HID / 4; ++k4) {
            float4 hv0 = h04[k4];
            float4 hv1 = h14[k4];
            float4 xv0 = x04[k4];
            float4 xv1 = x14[k4];
            int k = k4 * 4;
            #pragma unroll
            for (int u = 0; u < 4; ++u) {
                float wxv = wx[(size_t)(k + u) * HID];
                float whv = wh[(size_t)(k + u) * HID];
                float he0 = (u == 0) ? hv0.x : (u == 1) ? hv0.y : (u == 2) ? hv0.z : hv0.w;
                float he1 = (u == 0) ? hv1.x : (u == 1) ? hv1.y : (u == 2) ? hv1.z : hv1.w;
                float xe0 = (u == 0) ? xv0.x : (u == 1) ? xv0.y : (u == 2) ? xv0.z : xv0.w;
                float xe1 = (u == 0) ? xv1.x : (u == 1) ? xv1.y : (u == 2) ? xv1.z : xv1.w;
                acc0 += xe0 * wxv + he0 * whv;
                acc1 += xe1 * wxv + he1 * whv;
            }
        }

        float n0 = tanhf(acc0);
        float n1 = tanhf(acc1);
        __syncthreads();
        h0[j] = n0;
        h1[j] = n1;
        __syncthreads();
    }

    out[(size_t)b0 * HID + j] = h0[j];
    out[(size_t)b1 * HID + j] = h1[j];
}

// ---------------------------------------------------------------------------
extern "C" void kernel_launch(void* const* d_in, const int* in_sizes, int n_in,
                              void* d_out, int out_size, void* d_ws, size_t ws_size,
                              hipStream_t stream)
{
    const float* x    = (const float*)d_in[0];  // (128, 1024, 512)
    const float* Wx   = (const float*)d_in[1];  // (512, 512)
    const float* Wh   = (const float*)d_in[2];  // (512, 512)
    const float* bias = (const float*)d_in[3];  // (512,)
    float* out = (float*)d_out;                 // (128, 512)

    const size_t hBytes    = (size_t)BATCH * HID * sizeof(float);
    const size_t stepBytes = (size_t)BATCH * HID * sizeof(float);

    size_t xpCapSteps = (ws_size > hBytes) ? (ws_size - hBytes) / stepBytes : 0;

    if (xpCapSteps >= 1) {
        int chunk = (int)((xpCapSteps < (size_t)SEQ) ? xpCapSteps : (size_t)SEQ);
        float* h_state = (float*)d_ws;
        float* xp = (float*)((char*)d_ws + hBytes);

        int s0 = 0;
        int first = 1;
        while (s0 < SEQ) {
            int steps = (SEQ - s0 < chunk) ? (SEQ - s0) : chunk;
            dim3 ggrid((unsigned)(steps * BATCH / 64), HID / 64);
            xp_gemm<<<ggrid, 256, 0, stream>>>(x, Wx, bias, xp, s0);
            int last = (s0 + steps >= SEQ) ? 1 : 0;
            recur_kernel<<<BATCH / 2, HID, 0, stream>>>(xp, Wh, h_state, out,
                                                        steps, first, last);
            first = 0;
            s0 += steps;
        }
    } else {
        fused_kernel<<<BATCH / 2, HID, 0, stream>>>(x, Wx, Wh, bias, out);
    }
}

// Round 3
// 9791.718 us; speedup vs baseline: 6.1992x; 6.1992x over previous
//
#include <hip/hip_runtime.h>
#include <hip/hip_bf16.h>

// Problem: BATCH=128, SEQ=1024, DIN=512, HID=512 (all fp32)
// out = final hidden state (128, 512) of h_t = tanh(x_t@Wx + h_{t-1}@Wh + b)
//
// R3 design: column-split recurrence with register-resident Wh slices.
//  - 128 blocks = 16 batch-groups (8 rows) x 8 col-groups (64 cols).
//  - Each block holds Wh[:, its 64 cols] in VGPRs (64 regs/thread), loaded ONCE.
//    => total Wh global traffic 16 MB/dispatch (R2's per-step streaming hit 48 GB).
//  - Per step: MAC partials (k-split over 16 thread-groups) -> LDS reduce ->
//    tanh -> publish 8x64 h-slice to LLC (agent-scope) -> flag; consumers spin
//    on the 8 producer flags of their batch-group, then pull h into LDS.
//  - Ping-pong hxT buffers; flags are monotone step counters (zeroed by a
//    prefix kernel each call). Groups of 8 blocks share blockIdx%8 (XCD
//    round-robin heuristic for LLC locality; correctness is placement-free).

#define BATCH 128
#define SEQ   1024
#define DIN   512
#define HID   512

#define NG  16   // batch groups
#define NC  8    // col groups
#define RPB 8    // rows per block
#define CPB 64   // cols per block

typedef float v2f __attribute__((ext_vector_type(2)));

// ---------------------------------------------------------------------------
// Kernel 1: xp[s][b][j] = sum_d x[b][s][d] * Wx[d][j] + bias[j]   (unchanged)
// ---------------------------------------------------------------------------
__global__ __launch_bounds__(256) void xp_gemm(
    const float* __restrict__ x, const float* __restrict__ Wx,
    const float* __restrict__ bias, float* __restrict__ xp,
    int s0)
{
    __shared__ __align__(16) float As[16][64 + 4];
    __shared__ __align__(16) float Bs[16][64];

    const int tid = threadIdx.x;
    const int tx = tid & 15;
    const int ty = tid >> 4;
    const int rowBase = blockIdx.x * 64;
    const int colBase = blockIdx.y * 64;

    const int a_r  = tid >> 2;
    const int a_k4 = (tid & 3) * 4;
    const int rr   = rowBase + a_r;
    const int s    = s0 + (rr >> 7);
    const int bb   = rr & 127;
    const float* a_row = x + ((size_t)bb * SEQ + s) * DIN;

    const int b_kk = tid >> 4;
    const int b_j4 = (tid & 15) * 4;

    v2f C[4][2] = {};

    for (int k0 = 0; k0 < DIN; k0 += 16) {
        float4 av = *reinterpret_cast<const float4*>(a_row + k0 + a_k4);
        As[a_k4 + 0][a_r] = av.x;
        As[a_k4 + 1][a_r] = av.y;
        As[a_k4 + 2][a_r] = av.z;
        As[a_k4 + 3][a_r] = av.w;
        float4 bv = *reinterpret_cast<const float4*>(Wx + (size_t)(k0 + b_kk) * HID + colBase + b_j4);
        *reinterpret_cast<float4*>(&Bs[b_kk][b_j4]) = bv;
        __syncthreads();

        #pragma unroll
        for (int kk = 0; kk < 16; ++kk) {
            float4 a4 = *reinterpret_cast<const float4*>(&As[kk][ty * 4]);
            float4 b4 = *reinterpret_cast<const float4*>(&Bs[kk][tx * 4]);
            v2f b01 = {b4.x, b4.y};
            v2f b23 = {b4.z, b4.w};
            float a[4] = {a4.x, a4.y, a4.z, a4.w};
            #pragma unroll
            for (int i = 0; i < 4; ++i) {
                C[i][0] += b01 * a[i];
                C[i][1] += b23 * a[i];
            }
        }
        __syncthreads();
    }

    float4 bias4 = *reinterpret_cast<const float4*>(bias + colBase + tx * 4);
    #pragma unroll
    for (int i = 0; i < 4; ++i) {
        int orow = rowBase + ty * 4 + i;
        float4 o;
        o.x = C[i][0].x + bias4.x;
        o.y = C[i][0].y + bias4.y;
        o.z = C[i][1].x + bias4.z;
        o.w = C[i][1].y + bias4.w;
        *reinterpret_cast<float4*>(xp + (size_t)orow * HID + colBase + tx * 4) = o;
    }
}

// ---------------------------------------------------------------------------
// Flag init (flags live in re-poisoned ws -> must be zeroed every call)
// ---------------------------------------------------------------------------
__global__ void init_flags(unsigned int* flags)
{
    flags[threadIdx.x] = 0u;
}

// ---------------------------------------------------------------------------
// Kernel 2: column-split recurrence.
//   Block (cb, bb): rows [8bb, 8bb+8), cols [64cb, 64cb+64).
//   blockIdx = cb*NG + bb  (group members share blockIdx%8 -> same XCD under
//   round-robin dispatch; heuristic only).
//
//   MAC mapping:    tid = kg*32 + c2   (kg in [0,16): 32 k-rows; c2: col pair)
//   Reduce mapping: tid = rr*64 + cc   (rr: row, cc: col)
//
//   hxT global exchange layout: [buf][bb][k*8 + r], k = cb*64+cc global col.
// ---------------------------------------------------------------------------
__global__ __launch_bounds__(512, 2) void recur_kernel(
    const float* __restrict__ xp,       // chunk base: xp[s-s0][b][j]
    const float* __restrict__ Wh,
    float* __restrict__ out,
    unsigned int* __restrict__ flags,   // [NG*NC]
    unsigned int* __restrict__ hxT,     // [2][NG][HID*RPB]
    int s0, int steps)
{
    const int bb = blockIdx.x % NG;
    const int cb = blockIdx.x / NG;

    const int tid = threadIdx.x;
    const int c2 = tid & 31;     // col pair within slice
    const int kg = tid >> 5;     // k-group (32 rows each)
    const int rr = tid >> 6;     // reduce: row 0..7
    const int cc = tid & 63;     // reduce: col 0..63

    __shared__ __align__(16) float hT[HID * RPB];        // [k][r]  16 KB
    __shared__ __align__(16) float part[NG * RPB * CPB]; // [kg][r][c] 32 KB

    // ---- preload Wh slice into registers: w2[kk] = Wh[32kg+kk][64cb+2c2 ..+1]
    v2f w2[32];
    {
        const float* wbase = Wh + (size_t)(kg * 32) * HID + 64 * cb + 2 * c2;
        #pragma unroll
        for (int kk = 0; kk < 32; ++kk)
            w2[kk] = *reinterpret_cast<const v2f*>(wbase + (size_t)kk * HID);
    }

    const int send = s0 + steps;
    for (int s = s0; s < send; ++s) {
        // prefetch xp for this step (consumed at reduce time, ~1us later)
        float xpv = xp[((size_t)(s - s0) * BATCH + (RPB * bb + rr)) * HID + CPB * cb + cc];

        // ---- obtain h_s into hT
        if (s == 0) {
            #pragma unroll
            for (int i = 0; i < 8; ++i)
                hT[i * 512 + tid] = 0.0f;
        } else {
            if (tid < NC) {
                const unsigned target = (unsigned)s;
                while (__hip_atomic_load(&flags[bb * NC + tid],
                                         __ATOMIC_ACQUIRE,
                                         __HIP_MEMORY_SCOPE_AGENT) < target) { }
            }
            __syncthreads();
            const unsigned int* src = hxT + ((size_t)(s & 1) * NG + bb) * (HID * RPB);
            #pragma unroll
            for (int i = 0; i < 8; ++i) {
                int idx = i * 512 + tid;
                unsigned int u = __hip_atomic_load(&src[idx], __ATOMIC_RELAXED,
                                                   __HIP_MEMORY_SCOPE_AGENT);
                hT[idx] = __uint_as_float(u);
            }
        }
        __syncthreads();

        // ---- MAC phase: acc[r] (v2f over col pair) over 32 k-rows
        v2f acc[8] = {};
        const float* hk = &hT[(kg * 32) * RPB];
        #pragma unroll
        for (int kk = 0; kk < 32; ++kk) {
            float4 ha = *reinterpret_cast<const float4*>(hk + kk * RPB);
            float4 hb = *reinterpret_cast<const float4*>(hk + kk * RPB + 4);
            v2f w = w2[kk];
            acc[0] += w * ha.x;
            acc[1] += w * ha.y;
            acc[2] += w * ha.z;
            acc[3] += w * ha.w;
            acc[4] += w * hb.x;
            acc[5] += w * hb.y;
            acc[6] += w * hb.z;
            acc[7] += w * hb.w;
        }

        // ---- write partials: part[kg][r][c]
        #pragma unroll
        for (int r = 0; r < 8; ++r)
            *reinterpret_cast<v2f*>(&part[(kg * RPB + r) * CPB + 2 * c2]) = acc[r];
        __syncthreads();

        // ---- reduce across 16 k-groups, add xp, tanh
        float sum = xpv;
        #pragma unroll
        for (int g = 0; g < NG; ++g)
            sum += part[(g * RPB + rr) * CPB + cc];
        float hn = tanhf(sum);

        // ---- publish h_{s+1} slice (agent scope -> coherence point)
        unsigned int* dst = hxT + ((size_t)((s + 1) & 1) * NG + bb) * (HID * RPB);
        __hip_atomic_store(&dst[(CPB * cb + cc) * RPB + rr], __float_as_uint(hn),
                           __ATOMIC_RELAXED, __HIP_MEMORY_SCOPE_AGENT);
        if (s == SEQ - 1)
            out[(size_t)(RPB * bb + rr) * HID + CPB * cb + cc] = hn;

        // __syncthreads drains vmcnt before barrier -> all 512 threads' stores
        // are at the coherence point before the flag is released.
        __syncthreads();
        if (tid == 0)
            __hip_atomic_store(&flags[bb * NC + cb], (unsigned)(s + 1),
                               __ATOMIC_RELEASE, __HIP_MEMORY_SCOPE_AGENT);
        // hT/part reuse next iteration is protected by the barrier above plus
        // the fill-phase barrier at loop top.
    }
}

// ---------------------------------------------------------------------------
// Fallback (ws too small): fully fused, zero workspace.
// ---------------------------------------------------------------------------
__global__ __launch_bounds__(512) void fused_kernel(
    const float* __restrict__ x, const float* __restrict__ Wx,
    const float* __restrict__ Wh, const float* __restrict__ bias,
    float* __restrict__ out)
{
    __shared__ __align__(16) float h0[HID];
    __shared__ __align__(16) float h1[HID];
    __shared__ __align__(16) float x0[DIN];
    __shared__ __align__(16) float x1[DIN];

    const int j = threadIdx.x;
    const int b0 = blockIdx.x * 2;
    const int b1 = b0 + 1;

    h0[j] = 0.0f;
    h1[j] = 0.0f;
    __syncthreads();

    const float4* h04 = reinterpret_cast<const float4*>(h0);
    const float4* h14 = reinterpret_cast<const float4*>(h1);
    const float4* x04 = reinterpret_cast<const float4*>(x0);
    const float4* x14 = reinterpret_cast<const float4*>(x1);

    for (int s = 0; s < SEQ; ++s) {
        x0[j] = x[((size_t)b0 * SEQ + s) * DIN + j];
        x1[j] = x[((size_t)b1 * SEQ + s) * DIN + j];
        __syncthreads();

        float acc0 = bias[j];
        float acc1 = bias[j];
        const float* wx = Wx + j;
        const float* wh = Wh + j;
        #pragma unroll 2
        for (int k4 = 0; k4 < HID / 4; ++k4) {
            float4 hv0 = h04[k4];
            float4 hv1 = h14[k4];
            float4 xv0 = x04[k4];
            float4 xv1 = x14[k4];
            int k = k4 * 4;
            #pragma unroll
            for (int u = 0; u < 4; ++u) {
                float wxv = wx[(size_t)(k + u) * HID];
                float whv = wh[(size_t)(k + u) * HID];
                float he0 = (u == 0) ? hv0.x : (u == 1) ? hv0.y : (u == 2) ? hv0.z : hv0.w;
                float he1 = (u == 0) ? hv1.x : (u == 1) ? hv1.y : (u == 2) ? hv1.z : hv1.w;
                float xe0 = (u == 0) ? xv0.x : (u == 1) ? xv0.y : (u == 2) ? xv0.z : xv0.w;
                float xe1 = (u == 0) ? xv1.x : (u == 1) ? xv1.y : (u == 2) ? xv1.z : xv1.w;
                acc0 += xe0 * wxv + he0 * whv;
                acc1 += xe1 * wxv + he1 * whv;
            }
        }

        float n0 = tanhf(acc0);
        float n1 = tanhf(acc1);
        __syncthreads();
        h0[j] = n0;
        h1[j] = n1;
        __syncthreads();
    }

    out[(size_t)b0 * HID + j] = h0[j];
    out[(size_t)b1 * HID + j] = h1[j];
}

// ---------------------------------------------------------------------------
extern "C" void kernel_launch(void* const* d_in, const int* in_sizes, int n_in,
                              void* d_out, int out_size, void* d_ws, size_t ws_size,
                              hipStream_t stream)
{
    const float* x    = (const float*)d_in[0];  // (128, 1024, 512)
    const float* Wx   = (const float*)d_in[1];  // (512, 512)
    const float* Wh   = (const float*)d_in[2];  // (512, 512)
    const float* bias = (const float*)d_in[3];  // (512,)
    float* out = (float*)d_out;                 // (128, 512)

    const size_t flagsBytes = 4096;                                  // NG*NC*4 padded
    const size_t hxBytes    = 2ull * NG * (HID * RPB) * sizeof(float); // 512 KB
    const size_t stepBytes  = (size_t)BATCH * HID * sizeof(float);     // 256 KB
    const size_t fixed      = flagsBytes + hxBytes;

    size_t xpCapSteps = (ws_size > fixed) ? (ws_size - fixed) / stepBytes : 0;

    if (xpCapSteps >= 1) {
        unsigned int* flags = (unsigned int*)d_ws;
        unsigned int* hxT   = (unsigned int*)((char*)d_ws + flagsBytes);
        float* xp           = (float*)((char*)d_ws + fixed);

        init_flags<<<1, NG * NC, 0, stream>>>(flags);

        int chunk = (int)((xpCapSteps < (size_t)SEQ) ? xpCapSteps : (size_t)SEQ);
        int s0 = 0;
        while (s0 < SEQ) {
            int steps = (SEQ - s0 < chunk) ? (SEQ - s0) : chunk;
            dim3 ggrid((unsigned)(steps * BATCH / 64), HID / 64);
            xp_gemm<<<ggrid, 256, 0, stream>>>(x, Wx, bias, xp, s0);
            recur_kernel<<<NG * NC, 512, 0, stream>>>(xp, Wh, out, flags, hxT,
                                                      s0, steps);
            s0 += steps;
        }
    } else {
        fused_kernel<<<BATCH / 2, HID, 0, stream>>>(x, Wx, Wh, bias, out);
    }
}